// Round 8
// baseline (641.829 us; speedup 1.0000x reference)
//
#include <hip/hip_runtime.h>
#include <hip/hip_bf16.h>

// Shapes (fixed): B=2, L=2048 -> TOK=4096 tokens
#define TOKS 4096
#define DM   1024
#define DI   2048
#define DST  16
#define DTR  64
#define DFF  4096
#define PROJ_LD 128   // x_proj output padded 96 -> 128

// scan chunking
#define NC    32
#define CHUNK 64

typedef __bf16 bf16x8 __attribute__((ext_vector_type(8)));
typedef float  f32x4  __attribute__((ext_vector_type(4)));

__device__ __forceinline__ __bf16 f2bf(float f) {
  union { float f; unsigned u; } v; v.f = f;
  unsigned r = v.u + 0x7fffu + ((v.u >> 16) & 1u);
  union { unsigned short s; __bf16 b; } o; o.s = (unsigned short)(r >> 16);
  return o.b;
}
__device__ __forceinline__ float siluf(float x) { return x / (1.f + __expf(-x)); }
__device__ __forceinline__ float softplusf(float x) { return x > 20.f ? x : log1pf(__expf(x)); }

// async global->LDS, 16B per lane; LDS dest is wave-uniform base + lane*16
__device__ __forceinline__ void gl2lds16(const void* g, void* l) {
  __builtin_amdgcn_global_load_lds((const __attribute__((address_space(1))) void*)g,
                                   (__attribute__((address_space(3))) void*)l, 16, 0, 0);
}

// ---------------------------------------------------------------------------
// Fused f32 -> bf16 conversion, 5 flat weight tensors.
// ---------------------------------------------------------------------------
struct CvtArgs {
  const float* src[5];
  __bf16*      dst[5];
  int nblk[6];
};

__global__ __launch_bounds__(256) void cvt_bf16_kernel(CvtArgs a) {
  int blk = blockIdx.x;
  int seg = 0;
#pragma unroll
  for (int s = 1; s < 5; s++) if (blk >= a.nblk[s]) seg = s;
  size_t base = (size_t)(blk - a.nblk[seg]) * 2048 + threadIdx.x * 8;
  const float* src = a.src[seg] + base;
  __bf16*      dst = a.dst[seg] + base;
  float4 v0 = *(const float4*)src;
  float4 v1 = *(const float4*)(src + 4);
  union { __bf16 b[8]; uint4 u; } t;
  t.b[0]=f2bf(v0.x); t.b[1]=f2bf(v0.y); t.b[2]=f2bf(v0.z); t.b[3]=f2bf(v0.w);
  t.b[4]=f2bf(v1.x); t.b[5]=f2bf(v1.y); t.b[6]=f2bf(v1.z); t.b[7]=f2bf(v1.w);
  *(uint4*)dst = t.u;
}

// w1,w2 -> packed b_w12: 16-row interleave. dst row (r>>4)*32 + (r&15) + 16*isw2.
__global__ __launch_bounds__(256) void cvt_w12_kernel(const float* __restrict__ w1,
                                                      const float* __restrict__ w2,
                                                      __bf16* __restrict__ dst) {
  int blk = blockIdx.x;              // 0..4095
  int isw2 = blk >> 11;
  int b = blk & 2047;                // 2 rows per block
  int r = b * 2 + (threadIdx.x >> 7);
  int col = (threadIdx.x & 127) * 8;
  const float* src = (isw2 ? w2 : w1) + (size_t)r * DM + col;
  int dr = (r >> 4) * 32 + (r & 15) + isw2 * 16;
  float4 v0 = *(const float4*)src;
  float4 v1 = *(const float4*)(src + 4);
  union { __bf16 b[8]; uint4 u; } t;
  t.b[0]=f2bf(v0.x); t.b[1]=f2bf(v0.y); t.b[2]=f2bf(v0.z); t.b[3]=f2bf(v0.w);
  t.b[4]=f2bf(v1.x); t.b[5]=f2bf(v1.y); t.b[6]=f2bf(v1.z); t.b[7]=f2bf(v1.w);
  *(uint4*)&dst[(size_t)dr * DM + col] = t.u;
}

// ---------------------------------------------------------------------------
// RMSNorm: one block per row of 1024 f32, output bf16.
// ---------------------------------------------------------------------------
__global__ __launch_bounds__(256) void rmsnorm_kernel(const float* __restrict__ x,
                                                      const float* __restrict__ w,
                                                      __bf16* __restrict__ out) {
  int row = blockIdx.x;
  const float* xr = x + (size_t)row * DM;
  float4 v = ((const float4*)xr)[threadIdx.x];
  float ss = v.x*v.x + v.y*v.y + v.z*v.z + v.w*v.w;
#pragma unroll
  for (int o = 32; o > 0; o >>= 1) ss += __shfl_xor(ss, o);
  __shared__ float sred[4];
  if ((threadIdx.x & 63) == 0) sred[threadIdx.x >> 6] = ss;
  __syncthreads();
  float tot = sred[0] + sred[1] + sred[2] + sred[3];
  float scale = rsqrtf(tot * (1.f / DM) + 1e-5f);
  float4 wv = ((const float4*)w)[threadIdx.x];
  union { __bf16 b[4]; ushort4 u; } o;
  o.b[0] = f2bf(v.x * scale * wv.x);
  o.b[1] = f2bf(v.y * scale * wv.y);
  o.b[2] = f2bf(v.z * scale * wv.z);
  o.b[3] = f2bf(v.w * scale * wv.w);
  *(ushort4*)&out[(size_t)row * DM + threadIdx.x * 4] = o.u;
}

// ---------------------------------------------------------------------------
// GEMM: C[M,N] = A[M,K] @ B[N,K]^T. BM=256, BN=128, BK=32, 4 waves.
// Wave tile 128x64 (FM=8 x 4 frags): 12 ds_read_b128 per 32 MFMA
// (0.375 b128/MFMA, was 0.5) -- LDS pipe was the binding resource (r7).
// Single-buffered, compile-time geometry, quad-contiguous DMA staging.
// SWAP=1: blockIdx.x indexes M so A-sharing blocks share an XCD.
// EPI: 1 bf16, 2 softplus(acc+bias[col]) -> bf16, 3 acc+aux f32,
//      6 packed-SwiGLU silu(acc[j-1])*acc[j] bf16,
//      7 split-K partial f32 store at slice blockIdx.z
// ---------------------------------------------------------------------------
template<int EPI, int SWAP, int KK, int Z, int LDA, int LDB, int LDC>
__global__ __launch_bounds__(256, 2) void gemm2(
    const void* __restrict__ Ap, const __bf16* __restrict__ Bp,
    void* __restrict__ Cp, const void* __restrict__ auxp)
{
  constexpr int BM = 256;
  constexpr int FM = 8;                // frag rows per wave (wave tile 128x64)
  constexpr int kPer = KK / Z;
  __shared__ __bf16 sA[BM * 32];       // 16 KB
  __shared__ __bf16 sB[128 * 32];      // 8 KB
  const int tid  = threadIdx.x;
  const int wave = tid >> 6, lane = tid & 63;
  const int bm = SWAP ? blockIdx.x : blockIdx.y;
  const int bn = SWAP ? blockIdx.y : blockIdx.x;
  const int m0 = bm * BM, n0 = bn * 128;
  const int wr = wave >> 1, wc = wave & 1;
  const int frow = lane & 15, fq = lane >> 4;

  f32x4 acc[FM][4] = {};

  const int kBeg = (Z > 1) ? blockIdx.z * kPer : 0;
  const int kEnd = kBeg + kPer;

  const int lrow = lane >> 2;          // 4 lanes per 64B row segment
  const int lcol = (lane & 3) * 8;

  for (int kt = kBeg; kt < kEnd; kt += 32) {
#pragma unroll
    for (int q = 0; q < 4; q++) {      // A: 256x32 tile, 16 KB
      int idx = wave * 4 + q;
      gl2lds16((const __bf16*)Ap + (size_t)(m0 + idx * 16 + lrow) * LDA + kt + lcol,
               &sA[idx * 512]);
    }
#pragma unroll
    for (int q = 0; q < 2; q++) {      // B: 128x32 tile, 8 KB
      int idx = wave * 2 + q;
      gl2lds16(Bp + (size_t)(n0 + idx * 16 + lrow) * LDB + kt + lcol, &sB[idx * 512]);
    }
    __syncthreads();

    bf16x8 afr[FM], bfr[4];
#pragma unroll
    for (int i = 0; i < FM; i++)
      afr[i] = *(const bf16x8*)&sA[(wr * 128 + i * 16 + frow) * 32 + fq * 8];
#pragma unroll
    for (int j = 0; j < 4; j++)
      bfr[j] = *(const bf16x8*)&sB[(wc * 64 + j * 16 + frow) * 32 + fq * 8];
#pragma unroll
    for (int i = 0; i < FM; i++)
#pragma unroll
      for (int j = 0; j < 4; j++)
        acc[i][j] = __builtin_amdgcn_mfma_f32_16x16x32_bf16(afr[i], bfr[j], acc[i][j], 0, 0, 0);
    __syncthreads();
  }

  const float* auxf = (const float*)auxp;
#pragma unroll
  for (int i = 0; i < FM; i++) {
    int gr = m0 + wr * 128 + i * 16 + fq * 4;
#pragma unroll
    for (int j = 0; j < 4; j++) {
      int gc = n0 + wc * 64 + j * 16 + frow;
#pragma unroll
      for (int r = 0; r < 4; r++) {
        float v = acc[i][j][r];
        if (EPI == 6) {
          if (j & 1) {
            int col = (n0 >> 1) + 32 * wc + 16 * (j >> 1) + frow;
            size_t off = (size_t)(gr + r) * LDC + col;
            float g = acc[i][j-1][r];
            ((__bf16*)Cp)[off] = f2bf(siluf(g) * v);
          }
        } else {
          size_t off = (size_t)(gr + r) * LDC + gc;
          if (EPI == 1) ((__bf16*)Cp)[off] = f2bf(v);
          else if (EPI == 2) ((__bf16*)Cp)[off] = f2bf(softplusf(v + auxf[gc]));
          else if (EPI == 3) ((float*)Cp)[off] = v + auxf[off];
          else if (EPI == 7)
            ((float*)Cp)[(size_t)blockIdx.z * (TOKS * PROJ_LD) + off] = v;
        }
      }
    }
  }
}

// sum 8 split-K partial slices -> proj (f32) + bf16 copy of dt_r cols (0..63)
__global__ __launch_bounds__(256) void xp_reduce_kernel(const float* __restrict__ part,
                                                        float* __restrict__ proj,
                                                        __bf16* __restrict__ projb) {
  int i = blockIdx.x * 256 + threadIdx.x;        // float4 index, 131072 total
  float4 s = ((const float4*)part)[i];
#pragma unroll
  for (int z = 1; z < 8; z++) {
    float4 v = ((const float4*)(part + (size_t)z * TOKS * PROJ_LD))[i];
    s.x += v.x; s.y += v.y; s.z += v.z; s.w += v.w;
  }
  ((float4*)proj)[i] = s;
  int c4 = i & 31;                      // float4 column group within token
  if (c4 < 16) {                        // dt_r region: cols 0..63
    int tok = i >> 5;
    union { __bf16 b[4]; ushort4 u; } t;
    t.b[0]=f2bf(s.x); t.b[1]=f2bf(s.y); t.b[2]=f2bf(s.z); t.b[3]=f2bf(s.w);
    *(ushort4*)&projb[(size_t)tok * 64 + c4 * 4] = t.u;
  }
}

// ---------------------------------------------------------------------------
// Causal depthwise conv (width 4) + SiLU.
// ---------------------------------------------------------------------------
__global__ __launch_bounds__(256) void conv_silu_kernel(const __bf16* __restrict__ xz,
                                                        const float* __restrict__ cw,
                                                        const float* __restrict__ cb,
                                                        __bf16* __restrict__ uact) {
  int idx = blockIdx.x * 256 + threadIdx.x;
  int d   = idx & (DI - 1);
  int tok = idx >> 11;
  int l   = tok & 2047;
  float4 wv = *(const float4*)(cw + d * 4);
  const __bf16* up = xz + (size_t)tok * (2 * DI) + d;
  float acc = cb[d];
  if (l >= 3) acc += wv.x * (float)up[-3 * (2 * DI)];
  if (l >= 2) acc += wv.y * (float)up[-2 * (2 * DI)];
  if (l >= 1) acc += wv.z * (float)up[-1 * (2 * DI)];
  acc += wv.w * (float)up[0];
  uact[idx] = f2bf(siluf(acc));
}

// ---------------------------------------------------------------------------
// Selective scan, chunked 2-pass linear recurrence (proj stride = PROJ_LD).
// ---------------------------------------------------------------------------
__global__ __launch_bounds__(64) void scan_pass1(const __bf16* __restrict__ dt,
                                                 const __bf16* __restrict__ uact,
                                                 const float* __restrict__ proj,
                                                 const float* __restrict__ A_log,
                                                 float* __restrict__ aprod,
                                                 float* __restrict__ hend) {
  int lane = threadIdx.x;
  int d = blockIdx.x * 64 + lane;
  int c = blockIdx.y, b = blockIdx.z;
  float An[16], h[16], ap[16];
  {
    const float4* a4 = (const float4*)(A_log + (size_t)d * 16);
#pragma unroll
    for (int q = 0; q < 4; q++) {
      float4 v = a4[q];
      An[q*4+0] = -__expf(v.x); An[q*4+1] = -__expf(v.y);
      An[q*4+2] = -__expf(v.z); An[q*4+3] = -__expf(v.w);
    }
  }
#pragma unroll
  for (int n = 0; n < 16; n++) { h[n] = 0.f; ap[n] = 1.f; }

  size_t tok = (size_t)b * 2048 + (size_t)c * CHUNK;
  const __bf16* dtp = dt   + tok * DI + d;
  const __bf16* up  = uact + tok * DI + d;
  const float*  pp  = proj + tok * PROJ_LD;

  for (int t = 0; t < CHUNK; t++) {
    float dtv = (float)*dtp;
    float uv  = (float)*up;
    const float4* b4 = (const float4*)(pp + 64);
    float Bv[16];
#pragma unroll
    for (int q = 0; q < 4; q++) {
      float4 v = b4[q];
      Bv[q*4+0]=v.x; Bv[q*4+1]=v.y; Bv[q*4+2]=v.z; Bv[q*4+3]=v.w;
    }
    float du = dtv * uv;
#pragma unroll
    for (int n = 0; n < 16; n++) {
      float dA = __expf(dtv * An[n]);
      ap[n] *= dA;
      h[n] = fmaf(dA, h[n], du * Bv[n]);
    }
    dtp += DI; up += DI; pp += PROJ_LD;
  }

  size_t off = ((size_t)(b * NC + c) * DI + d) * 16;
#pragma unroll
  for (int q = 0; q < 4; q++) {
    *(float4*)(hend  + off + q*4) = make_float4(h[q*4+0],  h[q*4+1],  h[q*4+2],  h[q*4+3]);
    *(float4*)(aprod + off + q*4) = make_float4(ap[q*4+0], ap[q*4+1], ap[q*4+2], ap[q*4+3]);
  }
}

__global__ __launch_bounds__(256) void scan_pass2(const float* __restrict__ aprod,
                                                  const float* __restrict__ hend,
                                                  float* __restrict__ hstart) {
  int idx = blockIdx.x * 256 + threadIdx.x;
  int b  = idx >> 13;
  int r4 = idx & 8191;
  float4 H = make_float4(0.f, 0.f, 0.f, 0.f);
  for (int c = 0; c < NC; c++) {
    size_t off = (size_t)(b * NC + c) * (DI * 16 / 4) + r4;
    ((float4*)hstart)[off] = H;
    float4 a = ((const float4*)aprod)[off];
    float4 e = ((const float4*)hend)[off];
    H.x = fmaf(a.x, H.x, e.x);
    H.y = fmaf(a.y, H.y, e.y);
    H.z = fmaf(a.z, H.z, e.z);
    H.w = fmaf(a.w, H.w, e.w);
  }
}

__global__ __launch_bounds__(64) void scan_pass3(const __bf16* __restrict__ dt,
                                                 const __bf16* __restrict__ uact,
                                                 const float* __restrict__ proj,
                                                 const __bf16* __restrict__ xz,
                                                 const float* __restrict__ A_log,
                                                 const float* __restrict__ Dp,
                                                 const float* __restrict__ hstart,
                                                 __bf16* __restrict__ y) {
  int lane = threadIdx.x;
  int d = blockIdx.x * 64 + lane;
  int c = blockIdx.y, b = blockIdx.z;
  float An[16], h[16];
  {
    const float4* a4 = (const float4*)(A_log + (size_t)d * 16);
#pragma unroll
    for (int q = 0; q < 4; q++) {
      float4 v = a4[q];
      An[q*4+0] = -__expf(v.x); An[q*4+1] = -__expf(v.y);
      An[q*4+2] = -__expf(v.z); An[q*4+3] = -__expf(v.w);
    }
  }
  {
    size_t off = ((size_t)(b * NC + c) * DI + d) * 16;
#pragma unroll
    for (int q = 0; q < 4; q++) {
      float4 v = *(const float4*)(hstart + off + q*4);
      h[q*4+0]=v.x; h[q*4+1]=v.y; h[q*4+2]=v.z; h[q*4+3]=v.w;
    }
  }
  float Dd = Dp[d];

  size_t tok = (size_t)b * 2048 + (size_t)c * CHUNK;
  const __bf16* dtp = dt   + tok * DI + d;
  const __bf16* up  = uact + tok * DI + d;
  const float*  pp  = proj + tok * PROJ_LD;
  const __bf16* zp  = xz   + tok * (2 * DI) + DI + d;
  __bf16*       yp  = y    + tok * DI + d;

  for (int t = 0; t < CHUNK; t++) {
    float dtv = (float)*dtp;
    float uv  = (float)*up;
    float zv  = (float)*zp;
    const float4* b4 = (const float4*)(pp + 64);
    float Bv[16], Cv[16];
#pragma unroll
    for (int q = 0; q < 4; q++) {
      float4 v = b4[q];
      Bv[q*4+0]=v.x; Bv[q*4+1]=v.y; Bv[q*4+2]=v.z; Bv[q*4+3]=v.w;
      float4 w = b4[q + 4];
      Cv[q*4+0]=w.x; Cv[q*4+1]=w.y; Cv[q*4+2]=w.z; Cv[q*4+3]=w.w;
    }
    float du = dtv * uv;
    float p = 0.f;
#pragma unroll
    for (int n = 0; n < 16; n++) {
      float dA = __expf(dtv * An[n]);
      h[n] = fmaf(dA, h[n], du * Bv[n]);
      p = fmaf(h[n], Cv[n], p);
    }
    *yp = f2bf((p + Dd * uv) * siluf(zv));
    dtp += DI; up += DI; pp += PROJ_LD; zp += 2 * DI; yp += DI;
  }
}

// ---------------------------------------------------------------------------
extern "C" void kernel_launch(void* const* d_in, const int* in_sizes, int n_in,
                              void* d_out, int out_size, void* d_ws, size_t ws_size,
                              hipStream_t stream) {
  const float* x        = (const float*)d_in[0];
  const float* n1w      = (const float*)d_in[1];
  const float* n2w      = (const float*)d_in[2];
  const float* in_projw = (const float*)d_in[3];
  const float* conv_w   = (const float*)d_in[4];
  const float* conv_b   = (const float*)d_in[5];
  const float* x_projw  = (const float*)d_in[6];
  const float* dt_projw = (const float*)d_in[7];
  const float* dt_projb = (const float*)d_in[8];
  const float* A_log    = (const float*)d_in[9];
  const float* Dp       = (const float*)d_in[10];
  const float* out_projw= (const float*)d_in[11];
  const float* w1       = (const float*)d_in[12];
  const float* w2       = (const float*)d_in[13];
  const float* w3       = (const float*)d_in[14];
  float* out = (float*)d_out;

  char* ws = (char*)d_ws;
  __bf16* xz   = (__bf16*)(ws + 0);            // 4096x4096 bf16 = 33554432
  __bf16* uact = (__bf16*)(ws + 33554432);     // 4096x2048 bf16 = 16777216
  float*  proj = (float*) (ws + 50331648);     // 4096x128 f32  =  2097152
  __bf16* dt   = (__bf16*)(ws + 52428800);     // 4096x2048 bf16= 16777216
  __bf16* yb   = (__bf16*)(ws + 85983232);     // 4096x2048 bf16= 16777216
  float*  xpp  = (float*) (ws + 85983232);     // split-K partials 8x2MB (dead before yb written)
  float*  h    = (float*) (ws + 102760448);    // 4096x1024 f32 = 16777216
  __bf16* xn   = (__bf16*)(ws + 119537664);    // 4096x1024 bf16=  8388608
  __bf16* hid  = xz;                           // union: xz dead after scan_pass3
  // projb: bf16 dt_r cols, lives steps 4->5 only; overlaps aprod region
  __bf16* projb = (__bf16*)(ws + 102760448);   // 4096x64 bf16 = 524288
  float* aprod  = (float*)(ws + 102760448);    // overlaps h (h written at step 7)
  float* hend   = (float*)(ws + 111149056);
  float* hstart = (float*)(ws + 119537664);    // overlaps xn
  char* wb = ws + 127926272;
  __bf16* b_in  = (__bf16*)(wb);               // 8388608
  __bf16* b_xp  = (__bf16*)(wb + 8388608);     // 128x2048 (padded) = 524288
  __bf16* b_dtp = (__bf16*)(wb + 8912896);     // 262144
  __bf16* b_out = (__bf16*)(wb + 9175040);     // 4194304
  __bf16* b_w12 = (__bf16*)(wb + 13369344);    // 8192x1024 packed = 16777216
  __bf16* b_w3  = (__bf16*)(wb + 30146560);    // 8388608, end 38535168

  hipMemsetAsync(b_xp, 0, 128 * 2048 * sizeof(__bf16), stream);

  CvtArgs ca;
  const float* srcs[5] = {in_projw, x_projw, dt_projw, out_projw, w3};
  __bf16* dsts[5]      = {b_in, b_xp, b_dtp, b_out, b_w3};
  int counts[5] = {4096*1024, 96*2048, 2048*64, 1024*2048, 1024*4096};
  int acc = 0;
  for (int i = 0; i < 5; i++) { ca.src[i] = srcs[i]; ca.dst[i] = dsts[i]; ca.nblk[i] = acc; acc += counts[i] / 2048; }
  ca.nblk[5] = acc;
  cvt_bf16_kernel<<<acc, 256, 0, stream>>>(ca);
  cvt_w12_kernel<<<4096, 256, 0, stream>>>(w1, w2, b_w12);

  dim3 blk(256);
  // 1. xn = rmsnorm(x, norm1_w)
  rmsnorm_kernel<<<TOKS, 256, 0, stream>>>(x, n1w, xn);
  // 2. xz = xn @ in_proj_w.T          (4096x4096, K=1024) -> bf16
  gemm2<1,0, 1024,1, DM,DM,4096><<<dim3(32,16,1), blk, 0, stream>>>(xn, b_in, xz, nullptr);
  // 3. u_act = silu(causal_conv(u))   -> bf16
  conv_silu_kernel<<<(TOKS*DI)/256, 256, 0, stream>>>(xz, conv_w, conv_b, uact);
  // 4. x_proj split-K x8 -> partial slices, then reduce -> proj (+bf16 dt_r)
  gemm2<7,0, 2048,8, DI,DI,PROJ_LD><<<dim3(1,16,8), blk, 0, stream>>>(uact, b_xp, xpp, nullptr);
  xp_reduce_kernel<<<512, 256, 0, stream>>>(xpp, proj, projb);
  // 5. dt = softplus(dt_r @ dt_proj_w.T + b)   (4096x2048, K=64) -> bf16
  gemm2<2,0, 64,1, 64,DTR,DI><<<dim3(16,16,1), blk, 0, stream>>>(projb, b_dtp, dt, dt_projb);
  // 6. selective scan (chunked 2-pass) -> y (bf16)
  scan_pass1<<<dim3(DI/64, NC, 2), 64, 0, stream>>>(dt, uact, proj, A_log, aprod, hend);
  scan_pass2<<<64, 256, 0, stream>>>(aprod, hend, hstart);
  scan_pass3<<<dim3(DI/64, NC, 2), 64, 0, stream>>>(dt, uact, proj, xz, A_log, Dp, hstart, yb);
  // 7. h = y @ out_proj_w.T + x       (4096x1024, K=2048) -> f32, SWAP
  gemm2<3,1, 2048,1, DI,DI,DM><<<dim3(16,8,1), blk, 0, stream>>>(yb, b_out, h, x);
  // 8. xn = rmsnorm(h, norm2_w)
  rmsnorm_kernel<<<TOKS, 256, 0, stream>>>(h, n2w, xn);
  // 9+10 fused: hid = silu(xn@w1.T) * (xn@w2.T)  (packed N=8192) -> bf16 (overlays xz)
  gemm2<6,0, 1024,1, DM,DM,DFF><<<dim3(64,16,1), blk, 0, stream>>>(xn, b_w12, hid, nullptr);
  // 11. out = hid @ w3.T + h          (4096x1024, K=4096) -> f32, SWAP
  gemm2<3,1, 4096,1, DFF,DFF,DM><<<dim3(16,8,1), blk, 0, stream>>>(hid, b_w3, out, h);

  (void)in_sizes; (void)n_in; (void)out_size; (void)ws_size;
}

// Round 9
// 561.814 us; speedup vs baseline: 1.1424x; 1.1424x over previous
//
#include <hip/hip_runtime.h>
#include <hip/hip_bf16.h>

// Shapes (fixed): B=2, L=2048 -> TOK=4096 tokens
#define TOKS 4096
#define DM   1024
#define DI   2048
#define DST  16
#define DTR  64
#define DFF  4096
#define PROJ_LD 128   // x_proj output padded 96 -> 128

// scan chunking
#define NC    32
#define CHUNK 64

typedef __bf16 bf16x8 __attribute__((ext_vector_type(8)));
typedef float  f32x4  __attribute__((ext_vector_type(4)));

__device__ __forceinline__ __bf16 f2bf(float f) {
  union { float f; unsigned u; } v; v.f = f;
  unsigned r = v.u + 0x7fffu + ((v.u >> 16) & 1u);
  union { unsigned short s; __bf16 b; } o; o.s = (unsigned short)(r >> 16);
  return o.b;
}
__device__ __forceinline__ float siluf(float x) { return x / (1.f + __expf(-x)); }
__device__ __forceinline__ float softplusf(float x) { return x > 20.f ? x : log1pf(__expf(x)); }

// async global->LDS, 16B per lane; LDS dest is wave-uniform base + lane*16
__device__ __forceinline__ void gl2lds16(const void* g, void* l) {
  __builtin_amdgcn_global_load_lds((const __attribute__((address_space(1))) void*)g,
                                   (__attribute__((address_space(3))) void*)l, 16, 0, 0);
}

// ---------------------------------------------------------------------------
// Fused f32 -> bf16 conversion, 5 flat weight tensors.
// ---------------------------------------------------------------------------
struct CvtArgs {
  const float* src[5];
  __bf16*      dst[5];
  int nblk[6];
};

__global__ __launch_bounds__(256) void cvt_bf16_kernel(CvtArgs a) {
  int blk = blockIdx.x;
  int seg = 0;
#pragma unroll
  for (int s = 1; s < 5; s++) if (blk >= a.nblk[s]) seg = s;
  size_t base = (size_t)(blk - a.nblk[seg]) * 2048 + threadIdx.x * 8;
  const float* src = a.src[seg] + base;
  __bf16*      dst = a.dst[seg] + base;
  float4 v0 = *(const float4*)src;
  float4 v1 = *(const float4*)(src + 4);
  union { __bf16 b[8]; uint4 u; } t;
  t.b[0]=f2bf(v0.x); t.b[1]=f2bf(v0.y); t.b[2]=f2bf(v0.z); t.b[3]=f2bf(v0.w);
  t.b[4]=f2bf(v1.x); t.b[5]=f2bf(v1.y); t.b[6]=f2bf(v1.z); t.b[7]=f2bf(v1.w);
  *(uint4*)dst = t.u;
}

// w1,w2 -> packed b_w12: 16-row interleave. dst row (r>>4)*32 + (r&15) + 16*isw2.
__global__ __launch_bounds__(256) void cvt_w12_kernel(const float* __restrict__ w1,
                                                      const float* __restrict__ w2,
                                                      __bf16* __restrict__ dst) {
  int blk = blockIdx.x;              // 0..4095
  int isw2 = blk >> 11;
  int b = blk & 2047;                // 2 rows per block
  int r = b * 2 + (threadIdx.x >> 7);
  int col = (threadIdx.x & 127) * 8;
  const float* src = (isw2 ? w2 : w1) + (size_t)r * DM + col;
  int dr = (r >> 4) * 32 + (r & 15) + isw2 * 16;
  float4 v0 = *(const float4*)src;
  float4 v1 = *(const float4*)(src + 4);
  union { __bf16 b[8]; uint4 u; } t;
  t.b[0]=f2bf(v0.x); t.b[1]=f2bf(v0.y); t.b[2]=f2bf(v0.z); t.b[3]=f2bf(v0.w);
  t.b[4]=f2bf(v1.x); t.b[5]=f2bf(v1.y); t.b[6]=f2bf(v1.z); t.b[7]=f2bf(v1.w);
  *(uint4*)&dst[(size_t)dr * DM + col] = t.u;
}

// ---------------------------------------------------------------------------
// RMSNorm: one block per row of 1024 f32, output bf16.
// ---------------------------------------------------------------------------
__global__ __launch_bounds__(256) void rmsnorm_kernel(const float* __restrict__ x,
                                                      const float* __restrict__ w,
                                                      __bf16* __restrict__ out) {
  int row = blockIdx.x;
  const float* xr = x + (size_t)row * DM;
  float4 v = ((const float4*)xr)[threadIdx.x];
  float ss = v.x*v.x + v.y*v.y + v.z*v.z + v.w*v.w;
#pragma unroll
  for (int o = 32; o > 0; o >>= 1) ss += __shfl_xor(ss, o);
  __shared__ float sred[4];
  if ((threadIdx.x & 63) == 0) sred[threadIdx.x >> 6] = ss;
  __syncthreads();
  float tot = sred[0] + sred[1] + sred[2] + sred[3];
  float scale = rsqrtf(tot * (1.f / DM) + 1e-5f);
  float4 wv = ((const float4*)w)[threadIdx.x];
  union { __bf16 b[4]; ushort4 u; } o;
  o.b[0] = f2bf(v.x * scale * wv.x);
  o.b[1] = f2bf(v.y * scale * wv.y);
  o.b[2] = f2bf(v.z * scale * wv.z);
  o.b[3] = f2bf(v.w * scale * wv.w);
  *(ushort4*)&out[(size_t)row * DM + threadIdx.x * 4] = o.u;
}

// ---------------------------------------------------------------------------
// GEMM: C[M,N] = A[M,K] @ B[N,K]^T. BN=128, BK=32, 4 waves, single-buffered,
// compile-time geometry, quad-contiguous DMA staging.
// BM=128: wave tile 64x64 (r7-proven; use when grid would shrink below 2/CU).
// BM=256: wave tile 128x64, 0.375 b128/MFMA (use for wide-N GEMMs whose grid
//         stays >= 512 blocks: in_proj, w12).
// SWAP=1: blockIdx.x indexes M so A-sharing blocks share an XCD.
// EPI: 1 bf16, 2 softplus(acc+bias[col]) -> bf16, 3 acc+aux f32,
//      6 packed-SwiGLU silu(acc[j-1])*acc[j] bf16,
//      7 split-K partial f32 store at slice blockIdx.z
// ---------------------------------------------------------------------------
template<int BM, int EPI, int SWAP, int KK, int Z, int LDA, int LDB, int LDC>
__global__ __launch_bounds__(256, BM == 256 ? 2 : 1) void gemm2(
    const void* __restrict__ Ap, const __bf16* __restrict__ Bp,
    void* __restrict__ Cp, const void* __restrict__ auxp)
{
  constexpr int FM = BM / 32;          // frag rows per wave
  constexpr int AI = BM / 64;          // A staging instrs per wave
  constexpr int kPer = KK / Z;
  __shared__ __bf16 sA[BM * 32];
  __shared__ __bf16 sB[128 * 32];
  const int tid  = threadIdx.x;
  const int wave = tid >> 6, lane = tid & 63;
  const int bm = SWAP ? blockIdx.x : blockIdx.y;
  const int bn = SWAP ? blockIdx.y : blockIdx.x;
  const int m0 = bm * BM, n0 = bn * 128;
  const int wr = wave >> 1, wc = wave & 1;
  const int frow = lane & 15, fq = lane >> 4;

  f32x4 acc[FM][4] = {};

  const int kBeg = (Z > 1) ? blockIdx.z * kPer : 0;
  const int kEnd = kBeg + kPer;

  const int lrow = lane >> 2;          // 4 lanes per 64B row segment
  const int lcol = (lane & 3) * 8;

  for (int kt = kBeg; kt < kEnd; kt += 32) {
#pragma unroll
    for (int q = 0; q < AI; q++) {
      int idx = wave * AI + q;
      gl2lds16((const __bf16*)Ap + (size_t)(m0 + idx * 16 + lrow) * LDA + kt + lcol,
               &sA[idx * 512]);
    }
#pragma unroll
    for (int q = 0; q < 2; q++) {
      int idx = wave * 2 + q;
      gl2lds16(Bp + (size_t)(n0 + idx * 16 + lrow) * LDB + kt + lcol, &sB[idx * 512]);
    }
    __syncthreads();

    bf16x8 afr[FM], bfr[4];
#pragma unroll
    for (int i = 0; i < FM; i++)
      afr[i] = *(const bf16x8*)&sA[(wr * (BM/2) + i * 16 + frow) * 32 + fq * 8];
#pragma unroll
    for (int j = 0; j < 4; j++)
      bfr[j] = *(const bf16x8*)&sB[(wc * 64 + j * 16 + frow) * 32 + fq * 8];
#pragma unroll
    for (int i = 0; i < FM; i++)
#pragma unroll
      for (int j = 0; j < 4; j++)
        acc[i][j] = __builtin_amdgcn_mfma_f32_16x16x32_bf16(afr[i], bfr[j], acc[i][j], 0, 0, 0);
    __syncthreads();
  }

  const float* auxf = (const float*)auxp;
#pragma unroll
  for (int i = 0; i < FM; i++) {
    int gr = m0 + wr * (BM/2) + i * 16 + fq * 4;
#pragma unroll
    for (int j = 0; j < 4; j++) {
      int gc = n0 + wc * 64 + j * 16 + frow;
#pragma unroll
      for (int r = 0; r < 4; r++) {
        float v = acc[i][j][r];
        if (EPI == 6) {
          if (j & 1) {
            int col = (n0 >> 1) + 32 * wc + 16 * (j >> 1) + frow;
            size_t off = (size_t)(gr + r) * LDC + col;
            float g = acc[i][j-1][r];
            ((__bf16*)Cp)[off] = f2bf(siluf(g) * v);
          }
        } else {
          size_t off = (size_t)(gr + r) * LDC + gc;
          if (EPI == 1) ((__bf16*)Cp)[off] = f2bf(v);
          else if (EPI == 2) ((__bf16*)Cp)[off] = f2bf(softplusf(v + auxf[gc]));
          else if (EPI == 3) ((float*)Cp)[off] = v + auxf[off];
          else if (EPI == 7)
            ((float*)Cp)[(size_t)blockIdx.z * (TOKS * PROJ_LD) + off] = v;
        }
      }
    }
  }
}

// sum 8 split-K partial slices -> proj (f32) + bf16 copy of dt_r cols (0..63)
__global__ __launch_bounds__(256) void xp_reduce_kernel(const float* __restrict__ part,
                                                        float* __restrict__ proj,
                                                        __bf16* __restrict__ projb) {
  int i = blockIdx.x * 256 + threadIdx.x;        // float4 index, 131072 total
  float4 s = ((const float4*)part)[i];
#pragma unroll
  for (int z = 1; z < 8; z++) {
    float4 v = ((const float4*)(part + (size_t)z * TOKS * PROJ_LD))[i];
    s.x += v.x; s.y += v.y; s.z += v.z; s.w += v.w;
  }
  ((float4*)proj)[i] = s;
  int c4 = i & 31;                      // float4 column group within token
  if (c4 < 16) {                        // dt_r region: cols 0..63
    int tok = i >> 5;
    union { __bf16 b[4]; ushort4 u; } t;
    t.b[0]=f2bf(s.x); t.b[1]=f2bf(s.y); t.b[2]=f2bf(s.z); t.b[3]=f2bf(s.w);
    *(ushort4*)&projb[(size_t)tok * 64 + c4 * 4] = t.u;
  }
}

// ---------------------------------------------------------------------------
// Causal depthwise conv (width 4) + SiLU.
// ---------------------------------------------------------------------------
__global__ __launch_bounds__(256) void conv_silu_kernel(const __bf16* __restrict__ xz,
                                                        const float* __restrict__ cw,
                                                        const float* __restrict__ cb,
                                                        __bf16* __restrict__ uact) {
  int idx = blockIdx.x * 256 + threadIdx.x;
  int d   = idx & (DI - 1);
  int tok = idx >> 11;
  int l   = tok & 2047;
  float4 wv = *(const float4*)(cw + d * 4);
  const __bf16* up = xz + (size_t)tok * (2 * DI) + d;
  float acc = cb[d];
  if (l >= 3) acc += wv.x * (float)up[-3 * (2 * DI)];
  if (l >= 2) acc += wv.y * (float)up[-2 * (2 * DI)];
  if (l >= 1) acc += wv.z * (float)up[-1 * (2 * DI)];
  acc += wv.w * (float)up[0];
  uact[idx] = f2bf(siluf(acc));
}

// ---------------------------------------------------------------------------
// Selective scan, chunked 2-pass linear recurrence (proj stride = PROJ_LD).
// ---------------------------------------------------------------------------
__global__ __launch_bounds__(64) void scan_pass1(const __bf16* __restrict__ dt,
                                                 const __bf16* __restrict__ uact,
                                                 const float* __restrict__ proj,
                                                 const float* __restrict__ A_log,
                                                 float* __restrict__ aprod,
                                                 float* __restrict__ hend) {
  int lane = threadIdx.x;
  int d = blockIdx.x * 64 + lane;
  int c = blockIdx.y, b = blockIdx.z;
  float An[16], h[16], ap[16];
  {
    const float4* a4 = (const float4*)(A_log + (size_t)d * 16);
#pragma unroll
    for (int q = 0; q < 4; q++) {
      float4 v = a4[q];
      An[q*4+0] = -__expf(v.x); An[q*4+1] = -__expf(v.y);
      An[q*4+2] = -__expf(v.z); An[q*4+3] = -__expf(v.w);
    }
  }
#pragma unroll
  for (int n = 0; n < 16; n++) { h[n] = 0.f; ap[n] = 1.f; }

  size_t tok = (size_t)b * 2048 + (size_t)c * CHUNK;
  const __bf16* dtp = dt   + tok * DI + d;
  const __bf16* up  = uact + tok * DI + d;
  const float*  pp  = proj + tok * PROJ_LD;

  for (int t = 0; t < CHUNK; t++) {
    float dtv = (float)*dtp;
    float uv  = (float)*up;
    const float4* b4 = (const float4*)(pp + 64);
    float Bv[16];
#pragma unroll
    for (int q = 0; q < 4; q++) {
      float4 v = b4[q];
      Bv[q*4+0]=v.x; Bv[q*4+1]=v.y; Bv[q*4+2]=v.z; Bv[q*4+3]=v.w;
    }
    float du = dtv * uv;
#pragma unroll
    for (int n = 0; n < 16; n++) {
      float dA = __expf(dtv * An[n]);
      ap[n] *= dA;
      h[n] = fmaf(dA, h[n], du * Bv[n]);
    }
    dtp += DI; up += DI; pp += PROJ_LD;
  }

  size_t off = ((size_t)(b * NC + c) * DI + d) * 16;
#pragma unroll
  for (int q = 0; q < 4; q++) {
    *(float4*)(hend  + off + q*4) = make_float4(h[q*4+0],  h[q*4+1],  h[q*4+2],  h[q*4+3]);
    *(float4*)(aprod + off + q*4) = make_float4(ap[q*4+0], ap[q*4+1], ap[q*4+2], ap[q*4+3]);
  }
}

__global__ __launch_bounds__(256) void scan_pass2(const float* __restrict__ aprod,
                                                  const float* __restrict__ hend,
                                                  float* __restrict__ hstart) {
  int idx = blockIdx.x * 256 + threadIdx.x;
  int b  = idx >> 13;
  int r4 = idx & 8191;
  float4 H = make_float4(0.f, 0.f, 0.f, 0.f);
  for (int c = 0; c < NC; c++) {
    size_t off = (size_t)(b * NC + c) * (DI * 16 / 4) + r4;
    ((float4*)hstart)[off] = H;
    float4 a = ((const float4*)aprod)[off];
    float4 e = ((const float4*)hend)[off];
    H.x = fmaf(a.x, H.x, e.x);
    H.y = fmaf(a.y, H.y, e.y);
    H.z = fmaf(a.z, H.z, e.z);
    H.w = fmaf(a.w, H.w, e.w);
  }
}

__global__ __launch_bounds__(64) void scan_pass3(const __bf16* __restrict__ dt,
                                                 const __bf16* __restrict__ uact,
                                                 const float* __restrict__ proj,
                                                 const __bf16* __restrict__ xz,
                                                 const float* __restrict__ A_log,
                                                 const float* __restrict__ Dp,
                                                 const float* __restrict__ hstart,
                                                 __bf16* __restrict__ y) {
  int lane = threadIdx.x;
  int d = blockIdx.x * 64 + lane;
  int c = blockIdx.y, b = blockIdx.z;
  float An[16], h[16];
  {
    const float4* a4 = (const float4*)(A_log + (size_t)d * 16);
#pragma unroll
    for (int q = 0; q < 4; q++) {
      float4 v = a4[q];
      An[q*4+0] = -__expf(v.x); An[q*4+1] = -__expf(v.y);
      An[q*4+2] = -__expf(v.z); An[q*4+3] = -__expf(v.w);
    }
  }
  {
    size_t off = ((size_t)(b * NC + c) * DI + d) * 16;
#pragma unroll
    for (int q = 0; q < 4; q++) {
      float4 v = *(const float4*)(hstart + off + q*4);
      h[q*4+0]=v.x; h[q*4+1]=v.y; h[q*4+2]=v.z; h[q*4+3]=v.w;
    }
  }
  float Dd = Dp[d];

  size_t tok = (size_t)b * 2048 + (size_t)c * CHUNK;
  const __bf16* dtp = dt   + tok * DI + d;
  const __bf16* up  = uact + tok * DI + d;
  const float*  pp  = proj + tok * PROJ_LD;
  const __bf16* zp  = xz   + tok * (2 * DI) + DI + d;
  __bf16*       yp  = y    + tok * DI + d;

  for (int t = 0; t < CHUNK; t++) {
    float dtv = (float)*dtp;
    float uv  = (float)*up;
    float zv  = (float)*zp;
    const float4* b4 = (const float4*)(pp + 64);
    float Bv[16], Cv[16];
#pragma unroll
    for (int q = 0; q < 4; q++) {
      float4 v = b4[q];
      Bv[q*4+0]=v.x; Bv[q*4+1]=v.y; Bv[q*4+2]=v.z; Bv[q*4+3]=v.w;
      float4 w = b4[q + 4];
      Cv[q*4+0]=w.x; Cv[q*4+1]=w.y; Cv[q*4+2]=w.z; Cv[q*4+3]=w.w;
    }
    float du = dtv * uv;
    float p = 0.f;
#pragma unroll
    for (int n = 0; n < 16; n++) {
      float dA = __expf(dtv * An[n]);
      h[n] = fmaf(dA, h[n], du * Bv[n]);
      p = fmaf(h[n], Cv[n], p);
    }
    *yp = f2bf((p + Dd * uv) * siluf(zv));
    dtp += DI; up += DI; pp += PROJ_LD; zp += 2 * DI; yp += DI;
  }
}

// ---------------------------------------------------------------------------
extern "C" void kernel_launch(void* const* d_in, const int* in_sizes, int n_in,
                              void* d_out, int out_size, void* d_ws, size_t ws_size,
                              hipStream_t stream) {
  const float* x        = (const float*)d_in[0];
  const float* n1w      = (const float*)d_in[1];
  const float* n2w      = (const float*)d_in[2];
  const float* in_projw = (const float*)d_in[3];
  const float* conv_w   = (const float*)d_in[4];
  const float* conv_b   = (const float*)d_in[5];
  const float* x_projw  = (const float*)d_in[6];
  const float* dt_projw = (const float*)d_in[7];
  const float* dt_projb = (const float*)d_in[8];
  const float* A_log    = (const float*)d_in[9];
  const float* Dp       = (const float*)d_in[10];
  const float* out_projw= (const float*)d_in[11];
  const float* w1       = (const float*)d_in[12];
  const float* w2       = (const float*)d_in[13];
  const float* w3       = (const float*)d_in[14];
  float* out = (float*)d_out;

  char* ws = (char*)d_ws;
  __bf16* xz   = (__bf16*)(ws + 0);            // 4096x4096 bf16 = 33554432
  __bf16* uact = (__bf16*)(ws + 33554432);     // 4096x2048 bf16 = 16777216
  float*  proj = (float*) (ws + 50331648);     // 4096x128 f32  =  2097152
  __bf16* dt   = (__bf16*)(ws + 52428800);     // 4096x2048 bf16= 16777216
  __bf16* yb   = (__bf16*)(ws + 85983232);     // 4096x2048 bf16= 16777216
  float*  xpp  = (float*) (ws + 85983232);     // split-K partials 8x2MB (dead before yb written)
  float*  h    = (float*) (ws + 102760448);    // 4096x1024 f32 = 16777216
  __bf16* xn   = (__bf16*)(ws + 119537664);    // 4096x1024 bf16=  8388608
  __bf16* hid  = xz;                           // union: xz dead after scan_pass3
  __bf16* projb = (__bf16*)(ws + 102760448);   // 4096x64 bf16, steps 4->5 only
  float* aprod  = (float*)(ws + 102760448);    // overlaps h (h written at step 7)
  float* hend   = (float*)(ws + 111149056);
  float* hstart = (float*)(ws + 119537664);    // overlaps xn
  char* wb = ws + 127926272;
  __bf16* b_in  = (__bf16*)(wb);               // 8388608
  __bf16* b_xp  = (__bf16*)(wb + 8388608);     // 128x2048 (padded) = 524288
  __bf16* b_dtp = (__bf16*)(wb + 8912896);     // 262144
  __bf16* b_out = (__bf16*)(wb + 9175040);     // 4194304
  __bf16* b_w12 = (__bf16*)(wb + 13369344);    // 8192x1024 packed = 16777216
  __bf16* b_w3  = (__bf16*)(wb + 30146560);    // 8388608, end 38535168

  hipMemsetAsync(b_xp, 0, 128 * 2048 * sizeof(__bf16), stream);

  CvtArgs ca;
  const float* srcs[5] = {in_projw, x_projw, dt_projw, out_projw, w3};
  __bf16* dsts[5]      = {b_in, b_xp, b_dtp, b_out, b_w3};
  int counts[5] = {4096*1024, 96*2048, 2048*64, 1024*2048, 1024*4096};
  int acc = 0;
  for (int i = 0; i < 5; i++) { ca.src[i] = srcs[i]; ca.dst[i] = dsts[i]; ca.nblk[i] = acc; acc += counts[i] / 2048; }
  ca.nblk[5] = acc;
  cvt_bf16_kernel<<<acc, 256, 0, stream>>>(ca);
  cvt_w12_kernel<<<4096, 256, 0, stream>>>(w1, w2, b_w12);

  dim3 blk(256);
  // 1. xn = rmsnorm(x, norm1_w)
  rmsnorm_kernel<<<TOKS, 256, 0, stream>>>(x, n1w, xn);
  // 2. xz = xn @ in_proj_w.T          (4096x4096, K=1024) -> bf16, BM=256
  gemm2<256,1,0, 1024,1, DM,DM,4096><<<dim3(32,16,1), blk, 0, stream>>>(xn, b_in, xz, nullptr);
  // 3. u_act = silu(causal_conv(u))   -> bf16
  conv_silu_kernel<<<(TOKS*DI)/256, 256, 0, stream>>>(xz, conv_w, conv_b, uact);
  // 4. x_proj split-K x8 -> partial slices, then reduce -> proj (+bf16 dt_r), BM=128
  gemm2<128,7,0, 2048,8, DI,DI,PROJ_LD><<<dim3(1,32,8), blk, 0, stream>>>(uact, b_xp, xpp, nullptr);
  xp_reduce_kernel<<<512, 256, 0, stream>>>(xpp, proj, projb);
  // 5. dt = softplus(dt_r @ dt_proj_w.T + b)   (4096x2048, K=64) -> bf16, BM=128
  gemm2<128,2,0, 64,1, 64,DTR,DI><<<dim3(16,32,1), blk, 0, stream>>>(projb, b_dtp, dt, dt_projb);
  // 6. selective scan (chunked 2-pass) -> y (bf16)
  scan_pass1<<<dim3(DI/64, NC, 2), 64, 0, stream>>>(dt, uact, proj, A_log, aprod, hend);
  scan_pass2<<<64, 256, 0, stream>>>(aprod, hend, hstart);
  scan_pass3<<<dim3(DI/64, NC, 2), 64, 0, stream>>>(dt, uact, proj, xz, A_log, Dp, hstart, yb);
  // 7. h = y @ out_proj_w.T + x       (4096x1024, K=2048) -> f32, BM=128 SWAP
  gemm2<128,3,1, 2048,1, DI,DI,DM><<<dim3(32,8,1), blk, 0, stream>>>(yb, b_out, h, x);
  // 8. xn = rmsnorm(h, norm2_w)
  rmsnorm_kernel<<<TOKS, 256, 0, stream>>>(h, n2w, xn);
  // 9+10 fused: hid = silu(xn@w1.T) * (xn@w2.T)  (packed N=8192) -> bf16, BM=256
  gemm2<256,6,0, 1024,1, DM,DM,DFF><<<dim3(64,16,1), blk, 0, stream>>>(xn, b_w12, hid, nullptr);
  // 11. out = hid @ w3.T + h          (4096x1024, K=4096) -> f32, BM=128 SWAP
  gemm2<128,3,1, 4096,1, DFF,DFF,DM><<<dim3(32,8,1), blk, 0, stream>>>(hid, b_w3, out, h);

  (void)in_sizes; (void)n_in; (void)out_size; (void)ws_size;
}